// Round 5
// baseline (251.370 us; speedup 1.0000x reference)
//
#include <hip/hip_runtime.h>
#include <cstddef>
#include <cstdint>

constexpr int B_ = 32;
constexpr int C_ = 512;
constexpr int N_ = 512;
constexpr int H_ = 8;
constexpr int FH_ = 1024;
constexpr float BN_EPS_ = 1e-5f;
constexpr float LOG2E_ = 1.44269504088896f;

typedef __attribute__((ext_vector_type(8))) short bf16x8;
typedef __attribute__((ext_vector_type(4))) short s16x4;
typedef __attribute__((ext_vector_type(4))) float f32x4;

enum { EPI_QKV = 0, EPI_BN1 = 1, EPI_GELU = 2, EPI_BN2 = 3 };

__device__ inline void gload_lds16(const void* g, void* l) {
    __builtin_amdgcn_global_load_lds(
        (const __attribute__((address_space(1))) void*)g,
        (__attribute__((address_space(3))) void*)l, 16, 0, 0);
}

__device__ inline short f2bf(float f) {
    union { float f; uint32_t u; } v; v.f = f;
    uint32_t r = v.u + 0x7fffu + ((v.u >> 16) & 1u);
    return (short)(r >> 16);
}

// ---------------------------------------------------------------------------
// all four weight matrices fp32 -> bf16 in one launch (dest is contiguous ws)
// ---------------------------------------------------------------------------
__global__ __launch_bounds__(256) void cvt_weights(
    const float* __restrict__ s0, const float* __restrict__ s1,
    const float* __restrict__ s2, const float* __restrict__ s3,
    short* __restrict__ d)
{
    // element-4-group counts: 196608 | 65536 | 131072 | 131072  (sum 524288)
    int i = blockIdx.x * 256 + threadIdx.x;
    const float* src;
    int local;
    if (i < 196608)      { src = s0; local = i; }
    else if (i < 262144) { src = s1; local = i - 196608; }
    else if (i < 393216) { src = s2; local = i - 262144; }
    else                 { src = s3; local = i - 393216; }
    f32x4 v = *(const f32x4*)&src[(size_t)local * 4];
    s16x4 o;
    o[0] = f2bf(v[0]); o[1] = f2bf(v[1]); o[2] = f2bf(v[2]); o[3] = f2bf(v[3]);
    *(s16x4*)&d[(size_t)i * 4] = o;
}

// ---------------------------------------------------------------------------
// x [B][C][N] fp32 -> xT [B][N][C] bf16
// ---------------------------------------------------------------------------
__global__ __launch_bounds__(256) void transpose_x(const float* __restrict__ x,
                                                   short* __restrict__ xT)
{
    __shared__ __align__(16) float s[64][65];
    const int b = blockIdx.z, c0 = blockIdx.x * 64, n0 = blockIdx.y * 64;
    const int t = threadIdx.x;
    const float* xb = x + ((size_t)b * C_ + c0) * N_ + n0;
    {
        int nl = t & 63, cl = t >> 6;
#pragma unroll
        for (int i = 0; i < 16; ++i)
            s[cl + i * 4][nl] = xb[(size_t)(cl + i * 4) * N_ + nl];
    }
    __syncthreads();
    short* xTb = xT + ((size_t)b * N_ + n0) * C_ + c0;
    {
        int cl = t & 63, nl = t >> 6;
#pragma unroll
        for (int i = 0; i < 16; ++i)
            xTb[(size_t)(nl + i * 4) * C_ + cl] = f2bf(s[cl][nl + i * 4]);
    }
}

// ---------------------------------------------------------------------------
// MFMA GEMM: Y[b][n][o] = sum_c A[b][n][c] * W[o][c]  (+ epilogue)
// 128x128 tile, BK=32, 256 threads (4 waves, 2x2), 16x16x32 bf16 MFMA.
// 2-phase prefetch: double-buffered LDS, stage(k+1) issued before compute(k),
// single __syncthreads (drains vmcnt) per K-step.
// ---------------------------------------------------------------------------
template <int EPI, int KD, int OSTR>
__global__ __launch_bounds__(256) void gemm_mfma(
    const short* __restrict__ A, const short* __restrict__ W,
    const float* __restrict__ bias,
    short* __restrict__ Yb, short* __restrict__ Yv, float* __restrict__ Yf,
    const float* __restrict__ res,
    const float* __restrict__ g, const float* __restrict__ bt,
    const float* __restrict__ mn, const float* __restrict__ vr)
{
    const int b  = blockIdx.z;
    const int o0 = blockIdx.x * 128;
    const int n0 = blockIdx.y * 128;
    const short* Ab = A + (size_t)b * 512 * KD;

    __shared__ __align__(16) short As[2][128 * 32];
    __shared__ __align__(16) short Bs[2][128 * 32];

    const int t = threadIdx.x;
    const int lane = t & 63, w = t >> 6;
    const int l15 = lane & 15, lg = lane >> 4;
    const int wr = w >> 1, wc = w & 1;

    const f32x4 zero4 = {0.f, 0.f, 0.f, 0.f};
    f32x4 acc[4][4];
#pragma unroll
    for (int i = 0; i < 4; ++i)
#pragma unroll
        for (int j = 0; j < 4; ++j) acc[i][j] = zero4;

    const int r0 = t >> 2;            // staging row (0..63), +64 for 2nd instr
    const int kb = (t & 3) * 8;       // staging k offset

#define GSTAGE(bufi, kk0)                                                        \
    do {                                                                         \
        gload_lds16(Ab + (size_t)(n0 + r0) * KD + (kk0) + kb,      &As[bufi][w * 512]);        \
        gload_lds16(Ab + (size_t)(n0 + r0 + 64) * KD + (kk0) + kb, &As[bufi][w * 512 + 2048]); \
        gload_lds16(W  + (size_t)(o0 + r0) * KD + (kk0) + kb,      &Bs[bufi][w * 512]);        \
        gload_lds16(W  + (size_t)(o0 + r0 + 64) * KD + (kk0) + kb, &Bs[bufi][w * 512 + 2048]); \
    } while (0)

    GSTAGE(0, 0);
    __syncthreads();

    int cur = 0;
    for (int k0 = 0; k0 < KD; k0 += 32) {
        if (k0 + 32 < KD) GSTAGE(cur ^ 1, k0 + 32);

        bf16x8 af[4], bf[4];
#pragma unroll
        for (int mi = 0; mi < 4; ++mi)
            af[mi] = *(const bf16x8*)&As[cur][(wr * 64 + mi * 16 + l15) * 32 + lg * 8];
#pragma unroll
        for (int ni = 0; ni < 4; ++ni)
            bf[ni] = *(const bf16x8*)&Bs[cur][(wc * 64 + ni * 16 + l15) * 32 + lg * 8];
#pragma unroll
        for (int mi = 0; mi < 4; ++mi)
#pragma unroll
            for (int ni = 0; ni < 4; ++ni)
                acc[mi][ni] = __builtin_amdgcn_mfma_f32_16x16x32_bf16(
                    af[mi], bf[ni], acc[mi][ni], 0, 0, 0);
        __syncthreads();            // drains vmcnt (prefetch) + lgkm, then barrier
        cur ^= 1;
    }
#undef GSTAGE

    // epilogue
#pragma unroll
    for (int mi = 0; mi < 4; ++mi) {
        const int nb = n0 + wr * 64 + mi * 16 + lg * 4;   // rows nb..nb+3
#pragma unroll
        for (int ni = 0; ni < 4; ++ni) {
            const int o = o0 + wc * 64 + ni * 16 + l15;
            const float bv = bias[o];
            f32x4 v = acc[mi][ni];
            if constexpr (EPI == EPI_QKV) {
                if (o0 < 1024) {
#pragma unroll
                    for (int r = 0; r < 4; ++r)
                        Yb[((size_t)b * 512 + nb + r) * 1024 + o] = f2bf(v[r] + bv);
                } else {
                    s16x4 pk;
#pragma unroll
                    for (int r = 0; r < 4; ++r) pk[r] = f2bf(v[r] + bv);
                    *(s16x4*)&Yv[((size_t)b * 512 + (o - 1024)) * 512 + nb] = pk;
                }
            } else if constexpr (EPI == EPI_BN1) {
                const float sc = g[o] * rsqrtf(vr[o] + BN_EPS_);
                const float sh = bt[o] - mn[o] * sc;
                f32x4 rr = *(const f32x4*)&res[((size_t)b * 512 + o) * 512 + nb];
#pragma unroll
                for (int r = 0; r < 4; ++r) {
                    float val = (v[r] + bv + rr[r]) * sc + sh;
                    Yb[((size_t)b * 512 + nb + r) * 512 + o] = f2bf(val);
                    Yf[((size_t)b * 512 + nb + r) * 512 + o] = val;
                }
            } else if constexpr (EPI == EPI_GELU) {
#pragma unroll
                for (int r = 0; r < 4; ++r) {
                    float val = v[r] + bv;
                    val = 0.5f * val * (1.0f + erff(val * 0.70710678118654752f));
                    Yb[((size_t)b * 512 + nb + r) * OSTR + o] = f2bf(val);
                }
            } else { // EPI_BN2 -> final fp32 out [b][o][n]
                const float sc = g[o] * rsqrtf(vr[o] + BN_EPS_);
                const float sh = bt[o] - mn[o] * sc;
                f32x4 ov;
#pragma unroll
                for (int r = 0; r < 4; ++r) {
                    float hres = res[((size_t)b * 512 + nb + r) * 512 + o];
                    ov[r] = (v[r] + bv + hres) * sc + sh;
                }
                *(f32x4*)&Yf[((size_t)b * 512 + o) * 512 + nb] = ov;
            }
        }
    }
}

// ---------------------------------------------------------------------------
// Attention (flash-style, MFMA). Block: (b, h, 64 q-rows), 4 waves x 16 rows.
// KVBLK=64, double-buffered K/V (2-phase prefetch), 1 barrier per tile
// (P-tile is wave-private -> no barrier around it). Softmax in exp2 domain.
// LDS = 52 KB -> 3 blocks/CU.
// ---------------------------------------------------------------------------
__global__ __launch_bounds__(256) void attn_mfma(
    const short* __restrict__ qkT, const short* __restrict__ vT,
    const float* __restrict__ rel, short* __restrict__ attnT)
{
    const int n0 = blockIdx.x * 64;
    const int h  = blockIdx.y;
    const int b  = blockIdx.z;
    const int t  = threadIdx.x;
    const int lane = t & 63, w = t >> 6;
    const int l15 = lane & 15, lg = lane >> 4;

    __shared__ __align__(16) short Qs[64 * 64];
    __shared__ __align__(16) short Ks[2][64 * 64];
    __shared__ __align__(16) short Vs[2][64 * 64];
    __shared__ __align__(16) short Ps[4][16 * 64];
    __shared__ __align__(16) float relh[1024];

    const short* qb = qkT + (size_t)b * 512 * 1024;
    const short* vb = vT + (size_t)b * 512 * 512;

    for (int i = t; i < 1023; i += 256) relh[i] = rel[i * H_ + h] * LOG2E_;

    // stage Q [64 r][64 d] (swizzled 16B blocks within each row)
#pragma unroll
    for (int i = 0; i < 2; ++i) {
        int fl = t * 8 + i * 2048;
        int r = fl >> 6;
        int blk = (fl >> 3) & 7;
        int d = ((blk ^ (r & 7)) << 3);
        gload_lds16(qb + (size_t)(n0 + r) * 1024 + h * 64 + d, &Qs[w * 512 + i * 2048]);
    }

#define KSTAGE(bufi, m0s)                                                        \
    do {                                                                         \
        _Pragma("unroll")                                                        \
        for (int i_ = 0; i_ < 2; ++i_) {                                         \
            int fl_ = t * 8 + i_ * 2048;                                         \
            int r_ = fl_ >> 6;                                                   \
            int blk_ = (fl_ >> 3) & 7;                                           \
            int d_ = ((blk_ ^ (r_ & 7)) << 3);                                   \
            gload_lds16(qb + (size_t)((m0s) + r_) * 1024 + 512 + h * 64 + d_,    \
                        &Ks[bufi][w * 512 + i_ * 2048]);                         \
        }                                                                        \
        _Pragma("unroll")                                                        \
        for (int i_ = 0; i_ < 2; ++i_) {                                         \
            int fl_ = t * 8 + i_ * 2048;                                         \
            int dr_ = fl_ >> 6;                                                  \
            int blk_ = (fl_ >> 3) & 7;                                           \
            int m_ = ((blk_ ^ (dr_ & 7)) << 3);                                  \
            gload_lds16(vb + (size_t)(h * 64 + dr_) * 512 + (m0s) + m_,          \
                        &Vs[bufi][w * 512 + i_ * 2048]);                         \
        }                                                                        \
    } while (0)

    KSTAGE(0, 0);
    __syncthreads();

    const f32x4 zero4 = {0.f, 0.f, 0.f, 0.f};
    f32x4 acc_o[4];
#pragma unroll
    for (int dj = 0; dj < 4; ++dj) acc_o[dj] = zero4;
    float rmax[4], rsum[4];
#pragma unroll
    for (int r = 0; r < 4; ++r) { rmax[r] = -3e38f; rsum[r] = 0.f; }

    const int qr = w * 16 + l15;
    bf16x8 aq[2];
#pragma unroll
    for (int kk = 0; kk < 2; ++kk)
        aq[kk] = *(const bf16x8*)&Qs[qr * 64 + (((kk * 4 + lg) ^ (qr & 7)) << 3)];

    int cur = 0;
    for (int tile = 0; tile < 8; ++tile) {
        const int m0 = tile * 64;
        if (tile < 7) KSTAGE(cur ^ 1, m0 + 64);

        // QK^T : S rows = w*16 + lg*4+reg, cols = m0 + ni*16 + l15
        f32x4 s[4];
#pragma unroll
        for (int ni = 0; ni < 4; ++ni) {
            int mr = ni * 16 + l15;
            f32x4 a = zero4;
#pragma unroll
            for (int kk = 0; kk < 2; ++kk) {
                bf16x8 bk = *(const bf16x8*)&Ks[cur][mr * 64 + (((kk * 4 + lg) ^ (mr & 7)) << 3)];
                a = __builtin_amdgcn_mfma_f32_16x16x32_bf16(aq[kk], bk, a, 0, 0, 0);
            }
            s[ni] = a;
        }

        // bias + online softmax (log2 domain: score*log2e, exp2)
        float scale[4];
#pragma unroll
        for (int reg = 0; reg < 4; ++reg) {
            const int nglob = n0 + w * 16 + lg * 4 + reg;
            float tmax = -3e38f;
#pragma unroll
            for (int ni = 0; ni < 4; ++ni) {
                int mglob = m0 + ni * 16 + l15;
                float sv = s[ni][reg] * (0.125f * LOG2E_) + relh[mglob - nglob + 511];
                s[ni][reg] = sv;
                tmax = fmaxf(tmax, sv);
            }
            tmax = fmaxf(tmax, __shfl_xor(tmax, 1));
            tmax = fmaxf(tmax, __shfl_xor(tmax, 2));
            tmax = fmaxf(tmax, __shfl_xor(tmax, 4));
            tmax = fmaxf(tmax, __shfl_xor(tmax, 8));
            const float nm = fmaxf(rmax[reg], tmax);
            scale[reg] = __builtin_amdgcn_exp2f(rmax[reg] - nm);
            rmax[reg] = nm;
            float ts = 0.f;
#pragma unroll
            for (int ni = 0; ni < 4; ++ni) {
                float p = __builtin_amdgcn_exp2f(s[ni][reg] - nm);
                s[ni][reg] = p;
                ts += p;
            }
            ts += __shfl_xor(ts, 1); ts += __shfl_xor(ts, 2);
            ts += __shfl_xor(ts, 4); ts += __shfl_xor(ts, 8);
            rsum[reg] = rsum[reg] * scale[reg] + ts;
        }
#pragma unroll
        for (int dj = 0; dj < 4; ++dj)
#pragma unroll
            for (int reg = 0; reg < 4; ++reg) acc_o[dj][reg] *= scale[reg];

        // write P to LDS (bf16, swizzled) — wave-private region, no barrier
#pragma unroll
        for (int ni = 0; ni < 4; ++ni)
#pragma unroll
            for (int reg = 0; reg < 4; ++reg) {
                int rl = lg * 4 + reg;
                int m = ni * 16 + l15;
                int blk = (m >> 3) ^ (rl & 7);
                Ps[w][rl * 64 + (blk << 3) + (m & 7)] = f2bf(s[ni][reg]);
            }

        // PV (compiler inserts lgkmcnt wait for same-wave Ps RAW)
#pragma unroll
        for (int kk = 0; kk < 2; ++kk) {
            bf16x8 ap = *(const bf16x8*)&Ps[w][l15 * 64 + (((kk * 4 + lg) ^ (l15 & 7)) << 3)];
#pragma unroll
            for (int dj = 0; dj < 4; ++dj) {
                int dr = dj * 16 + l15;
                bf16x8 bv = *(const bf16x8*)&Vs[cur][dr * 64 + (((kk * 4 + lg) ^ (dr & 7)) << 3)];
                acc_o[dj] = __builtin_amdgcn_mfma_f32_16x16x32_bf16(ap, bv, acc_o[dj], 0, 0, 0);
            }
        }
        __syncthreads();            // drains vmcnt (prefetch) before buffer swap
        cur ^= 1;
    }
#undef KSTAGE

    short* ob = attnT + (size_t)b * 512 * 512;
#pragma unroll
    for (int dj = 0; dj < 4; ++dj)
#pragma unroll
        for (int reg = 0; reg < 4; ++reg) {
            int nglob = n0 + w * 16 + lg * 4 + reg;
            ob[(size_t)nglob * 512 + h * 64 + dj * 16 + l15] =
                f2bf(acc_o[dj][reg] / rsum[reg]);
        }
}

// ---------------------------------------------------------------------------
extern "C" void kernel_launch(void* const* d_in, const int* in_sizes, int n_in,
                              void* d_out, int out_size, void* d_ws, size_t ws_size,
                              hipStream_t stream)
{
    const float* x      = (const float*)d_in[0];
    const float* qkv_w  = (const float*)d_in[1];
    const float* qkv_b  = (const float*)d_in[2];
    const float* out_w  = (const float*)d_in[3];
    const float* out_b  = (const float*)d_in[4];
    const float* rel    = (const float*)d_in[5];
    const float* bn1_g  = (const float*)d_in[6];
    const float* bn1_b  = (const float*)d_in[7];
    const float* bn1_m  = (const float*)d_in[8];
    const float* bn1_v  = (const float*)d_in[9];
    const float* ffn1_w = (const float*)d_in[10];
    const float* ffn1_b = (const float*)d_in[11];
    const float* ffn2_w = (const float*)d_in[12];
    const float* ffn2_b = (const float*)d_in[13];
    const float* bn2_g  = (const float*)d_in[14];
    const float* bn2_b  = (const float*)d_in[15];
    const float* bn2_m  = (const float*)d_in[16];
    const float* bn2_v  = (const float*)d_in[17];

    float* out = (float*)d_out;
    short* ws  = (short*)d_ws;

    size_t off = 0;
    short* qkvw_bf = ws + off; off += (size_t)1536 * 512;   // cvt dest is
    short* outw_bf = ws + off; off += (size_t)512 * 512;    // contiguous
    short* f1w_bf  = ws + off; off += (size_t)1024 * 512;   // across these 4
    short* f2w_bf  = ws + off; off += (size_t)512 * 1024;
    short* xT      = ws + off; off += (size_t)B_ * 512 * 512;
    short* qkT     = ws + off; off += (size_t)B_ * 512 * 1024;
    short* vTb     = ws + off; off += (size_t)B_ * 512 * 512;
    short* attnT   = ws + off; off += (size_t)B_ * 512 * 512;
    short* h_bf    = ws + off; off += (size_t)B_ * 512 * 512;
    short* f1_bf   = ws + off; off += (size_t)B_ * 512 * 1024;
    float* h_f32   = (float*)(ws + off);   // + B*512*512 floats

    const dim3 blk(256);

    // weight conversions (one launch, 524288 f32x4 groups)
    cvt_weights<<<dim3(524288 / 256), blk, 0, stream>>>(qkv_w, out_w, ffn1_w, ffn2_w, qkvw_bf);

    // x -> xT bf16
    transpose_x<<<dim3(8, 8, B_), blk, 0, stream>>>(x, xT);

    // 1) qkv projection (q,k -> qkT [n][1024]; v -> vTb [dv][n])
    gemm_mfma<EPI_QKV, 512, 1024><<<dim3(12, 4, B_), blk, 0, stream>>>(
        xT, qkvw_bf, qkv_b, qkT, vTb, nullptr, nullptr, nullptr, nullptr, nullptr, nullptr);

    // 2) attention
    attn_mfma<<<dim3(8, H_, B_), blk, 0, stream>>>(qkT, vTb, rel, attnT);

    // 3) out projection + residual(x) + BN1 -> h_bf + h_f32
    gemm_mfma<EPI_BN1, 512, 512><<<dim3(4, 4, B_), blk, 0, stream>>>(
        attnT, outw_bf, out_b, h_bf, nullptr, h_f32, x, bn1_g, bn1_b, bn1_m, bn1_v);

    // 4) ffn1 + GELU -> f1_bf
    gemm_mfma<EPI_GELU, 512, 1024><<<dim3(8, 4, B_), blk, 0, stream>>>(
        h_bf, f1w_bf, ffn1_b, f1_bf, nullptr, nullptr, nullptr, nullptr, nullptr, nullptr, nullptr);

    // 5) ffn2 + residual(h) + BN2 -> out fp32 [b][c][n]
    gemm_mfma<EPI_BN2, 1024, 512><<<dim3(4, 4, B_), blk, 0, stream>>>(
        f1_bf, f2w_bf, ffn2_b, nullptr, nullptr, out, h_f32, bn2_g, bn2_b, bn2_m, bn2_v);
}

// Round 7
// 218.368 us; speedup vs baseline: 1.1511x; 1.1511x over previous
//
#include <hip/hip_runtime.h>
#include <cstddef>
#include <cstdint>

constexpr int B_ = 32;
constexpr int C_ = 512;
constexpr int N_ = 512;
constexpr int H_ = 8;
constexpr int FH_ = 1024;
constexpr float BN_EPS_ = 1e-5f;
constexpr float LOG2E_ = 1.44269504088896f;

typedef __attribute__((ext_vector_type(8))) short bf16x8;
typedef __attribute__((ext_vector_type(4))) short s16x4;
typedef __attribute__((ext_vector_type(4))) float f32x4;

enum { EPI_QKV = 0, EPI_BN1 = 1, EPI_GELU = 2, EPI_BN2 = 3 };

__device__ inline void gload_lds16(const void* g, void* l) {
    __builtin_amdgcn_global_load_lds(
        (const __attribute__((address_space(1))) void*)g,
        (__attribute__((address_space(3))) void*)l, 16, 0, 0);
}

__device__ inline short f2bf(float f) {
    union { float f; uint32_t u; } v; v.f = f;
    uint32_t r = v.u + 0x7fffu + ((v.u >> 16) & 1u);
    return (short)(r >> 16);
}

__device__ inline float bf2f(short s) {
    union { uint32_t u; float f; } v;
    v.u = ((uint32_t)(uint16_t)s) << 16;
    return v.f;
}

__device__ inline uint32_t cvt_pk_bf16(float lo, float hi) {
    uint32_t r;
    asm("v_cvt_pk_bf16_f32 %0, %1, %2" : "=v"(r) : "v"(lo), "v"(hi));
    return r;
}

// ---------------------------------------------------------------------------
// all four weight matrices fp32 -> bf16 in one launch (dest contiguous in ws)
// ---------------------------------------------------------------------------
__global__ __launch_bounds__(256) void cvt_weights(
    const float* __restrict__ s0, const float* __restrict__ s1,
    const float* __restrict__ s2, const float* __restrict__ s3,
    short* __restrict__ d)
{
    int i = blockIdx.x * 256 + threadIdx.x;
    const float* src;
    int local;
    if (i < 196608)      { src = s0; local = i; }
    else if (i < 262144) { src = s1; local = i - 196608; }
    else if (i < 393216) { src = s2; local = i - 262144; }
    else                 { src = s3; local = i - 393216; }
    f32x4 v = *(const f32x4*)&src[(size_t)local * 4];
    s16x4 o;
    o[0] = f2bf(v[0]); o[1] = f2bf(v[1]); o[2] = f2bf(v[2]); o[3] = f2bf(v[3]);
    *(s16x4*)&d[(size_t)i * 4] = o;
}

// ---------------------------------------------------------------------------
// x [B][C][N] fp32 -> xT [B][N][C] bf16
// ---------------------------------------------------------------------------
__global__ __launch_bounds__(256) void transpose_x(const float* __restrict__ x,
                                                   short* __restrict__ xT)
{
    __shared__ __align__(16) float s[64][65];
    const int b = blockIdx.z, c0 = blockIdx.x * 64, n0 = blockIdx.y * 64;
    const int t = threadIdx.x;
    const float* xb = x + ((size_t)b * C_ + c0) * N_ + n0;
    {
        int nl = t & 63, cl = t >> 6;
#pragma unroll
        for (int i = 0; i < 16; ++i)
            s[cl + i * 4][nl] = xb[(size_t)(cl + i * 4) * N_ + nl];
    }
    __syncthreads();
    short* xTb = xT + ((size_t)b * N_ + n0) * C_ + c0;
    {
        int cl = t & 63, nl = t >> 6;
#pragma unroll
        for (int i = 0; i < 16; ++i)
            xTb[(size_t)(nl + i * 4) * C_ + cl] = f2bf(s[cl][nl + i * 4]);
    }
}

// ---------------------------------------------------------------------------
// MFMA GEMM: Y[b][n][o] = sum_c A[b][n][c] * W[o][c]  (+ epilogue)
// 128x128 tile, BK=32, 256 threads (4 waves, 2x2), 16x16x32 bf16 MFMA.
// Residuals (BN1/BN2) read as bf16 [b][n][c] (coalesced along o).
// ---------------------------------------------------------------------------
template <int EPI, int KD, int OSTR>
__global__ __launch_bounds__(256) void gemm_mfma(
    const short* __restrict__ A, const short* __restrict__ W,
    const float* __restrict__ bias,
    short* __restrict__ Yb, short* __restrict__ Yv, float* __restrict__ Yf,
    const short* __restrict__ resb,
    const float* __restrict__ g, const float* __restrict__ bt,
    const float* __restrict__ mn, const float* __restrict__ vr)
{
    const int b  = blockIdx.z;
    const int o0 = blockIdx.x * 128;
    const int n0 = blockIdx.y * 128;
    const short* Ab = A + (size_t)b * 512 * KD;

    __shared__ __align__(16) short As[2][128 * 32];
    __shared__ __align__(16) short Bs[2][128 * 32];

    const int t = threadIdx.x;
    const int lane = t & 63, w = t >> 6;
    const int l15 = lane & 15, lg = lane >> 4;
    const int wr = w >> 1, wc = w & 1;

    const f32x4 zero4 = {0.f, 0.f, 0.f, 0.f};
    f32x4 acc[4][4];
#pragma unroll
    for (int i = 0; i < 4; ++i)
#pragma unroll
        for (int j = 0; j < 4; ++j) acc[i][j] = zero4;

    const int r0 = t >> 2;            // staging row (0..63), +64 for 2nd instr
    const int kb = (t & 3) * 8;       // staging k offset

#define GSTAGE(bufi, kk0)                                                        \
    do {                                                                         \
        gload_lds16(Ab + (size_t)(n0 + r0) * KD + (kk0) + kb,      &As[bufi][w * 512]);        \
        gload_lds16(Ab + (size_t)(n0 + r0 + 64) * KD + (kk0) + kb, &As[bufi][w * 512 + 2048]); \
        gload_lds16(W  + (size_t)(o0 + r0) * KD + (kk0) + kb,      &Bs[bufi][w * 512]);        \
        gload_lds16(W  + (size_t)(o0 + r0 + 64) * KD + (kk0) + kb, &Bs[bufi][w * 512 + 2048]); \
    } while (0)

    GSTAGE(0, 0);
    __syncthreads();

    int cur = 0;
    for (int k0 = 0; k0 < KD; k0 += 32) {
        if (k0 + 32 < KD) GSTAGE(cur ^ 1, k0 + 32);

        bf16x8 af[4], bf[4];
#pragma unroll
        for (int mi = 0; mi < 4; ++mi)
            af[mi] = *(const bf16x8*)&As[cur][(wr * 64 + mi * 16 + l15) * 32 + lg * 8];
#pragma unroll
        for (int ni = 0; ni < 4; ++ni)
            bf[ni] = *(const bf16x8*)&Bs[cur][(wc * 64 + ni * 16 + l15) * 32 + lg * 8];
#pragma unroll
        for (int mi = 0; mi < 4; ++mi)
#pragma unroll
            for (int ni = 0; ni < 4; ++ni)
                acc[mi][ni] = __builtin_amdgcn_mfma_f32_16x16x32_bf16(
                    af[mi], bf[ni], acc[mi][ni], 0, 0, 0);
        __syncthreads();
        cur ^= 1;
    }
#undef GSTAGE

    // epilogue
#pragma unroll
    for (int mi = 0; mi < 4; ++mi) {
        const int nb = n0 + wr * 64 + mi * 16 + lg * 4;   // rows nb..nb+3
#pragma unroll
        for (int ni = 0; ni < 4; ++ni) {
            const int o = o0 + wc * 64 + ni * 16 + l15;
            const float bv = bias[o];
            f32x4 v = acc[mi][ni];
            if constexpr (EPI == EPI_QKV) {
                if (o0 < 1024) {
#pragma unroll
                    for (int r = 0; r < 4; ++r)
                        Yb[((size_t)b * 512 + nb + r) * 1024 + o] = f2bf(v[r] + bv);
                } else {
                    s16x4 pk;
#pragma unroll
                    for (int r = 0; r < 4; ++r) pk[r] = f2bf(v[r] + bv);
                    *(s16x4*)&Yv[((size_t)b * 512 + (o - 1024)) * 512 + nb] = pk;
                }
            } else if constexpr (EPI == EPI_BN1) {
                const float sc = g[o] * rsqrtf(vr[o] + BN_EPS_);
                const float sh = bt[o] - mn[o] * sc;
#pragma unroll
                for (int r = 0; r < 4; ++r) {
                    float rr = bf2f(resb[((size_t)b * 512 + nb + r) * 512 + o]);
                    float val = (v[r] + bv + rr) * sc + sh;
                    Yb[((size_t)b * 512 + nb + r) * 512 + o] = f2bf(val);
                }
            } else if constexpr (EPI == EPI_GELU) {
#pragma unroll
                for (int r = 0; r < 4; ++r) {
                    float val = v[r] + bv;
                    val = 0.5f * val * (1.0f + erff(val * 0.70710678118654752f));
                    Yb[((size_t)b * 512 + nb + r) * OSTR + o] = f2bf(val);
                }
            } else { // EPI_BN2 -> final fp32 out [b][o][n], residual h_bf
                const float sc = g[o] * rsqrtf(vr[o] + BN_EPS_);
                const float sh = bt[o] - mn[o] * sc;
                f32x4 ov;
#pragma unroll
                for (int r = 0; r < 4; ++r) {
                    float hres = bf2f(resb[((size_t)b * 512 + nb + r) * 512 + o]);
                    ov[r] = (v[r] + bv + hres) * sc + sh;
                }
                *(f32x4*)&Yf[((size_t)b * 512 + o) * 512 + nb] = ov;
            }
        }
    }
}

// ---------------------------------------------------------------------------
// Attention (flash-style, MFMA, SWAPPED QK^T). Block: (b, h, 64 q-rows).
// s = mfma(K_frag, Q_frag) -> S[m at lg*4+reg (+16*mi)][q at l15]:
// each lane owns ONE q-row -> softmax reduce = in-lane + 2 shfl_xor.
// Defer-max (THR=8 in log2 domain). P packed via v_cvt_pk_bf16_f32,
// 4x ds_write_b64 (XOR-swizzled), PV A-frag read matches GEMM layout.
// Grid 2048 1-D: h = id&7 (XCD affinity), n0 = ((id>>3)&7)*64, b = id>>6.
// ---------------------------------------------------------------------------
__global__ __launch_bounds__(256) void attn_mfma(
    const short* __restrict__ qkT, const short* __restrict__ vT,
    const float* __restrict__ rel, short* __restrict__ attnT)
{
    const int id = blockIdx.x;
    const int h  = id & 7;
    const int n0 = ((id >> 3) & 7) * 64;
    const int b  = id >> 6;
    const int t  = threadIdx.x;
    const int lane = t & 63, w = t >> 6;
    const int l15 = lane & 15, lg = lane >> 4;

    __shared__ __align__(16) short Qs[64 * 64];
    __shared__ __align__(16) short Ks[2][64 * 64];
    __shared__ __align__(16) short Vs[2][64 * 64];
    __shared__ __align__(16) short Ps[4 * 16 * 64];
    __shared__ __align__(16) float relh[1024];

    const short* qb = qkT + (size_t)b * 512 * 1024;
    const short* vb = vT + (size_t)b * 512 * 512;

    for (int i = t; i < 1023; i += 256) relh[i] = rel[i * H_ + h] * LOG2E_;

    // stage Q [64 r][64 d] (swizzled 16B blocks within each row)
#pragma unroll
    for (int i = 0; i < 2; ++i) {
        int fl = t * 8 + i * 2048;
        int r = fl >> 6;
        int blk = (fl >> 3) & 7;
        int d = ((blk ^ (r & 7)) << 3);
        gload_lds16(qb + (size_t)(n0 + r) * 1024 + h * 64 + d, &Qs[w * 512 + i * 2048]);
    }

#define KSTAGE(bufi, m0s)                                                        \
    do {                                                                         \
        _Pragma("unroll")                                                        \
        for (int i_ = 0; i_ < 2; ++i_) {                                         \
            int fl_ = t * 8 + i_ * 2048;                                         \
            int r_ = fl_ >> 6;                                                   \
            int blk_ = (fl_ >> 3) & 7;                                           \
            int d_ = ((blk_ ^ (r_ & 7)) << 3);                                   \
            gload_lds16(qb + (size_t)((m0s) + r_) * 1024 + 512 + h * 64 + d_,    \
                        &Ks[bufi][w * 512 + i_ * 2048]);                         \
        }                                                                        \
        _Pragma("unroll")                                                        \
        for (int i_ = 0; i_ < 2; ++i_) {                                         \
            int fl_ = t * 8 + i_ * 2048;                                         \
            int dr_ = fl_ >> 6;                                                  \
            int blk_ = (fl_ >> 3) & 7;                                           \
            int m_ = ((blk_ ^ (dr_ & 7)) << 3);                                  \
            gload_lds16(vb + (size_t)(h * 64 + dr_) * 512 + (m0s) + m_,          \
                        &Vs[bufi][w * 512 + i_ * 2048]);                         \
        }                                                                        \
    } while (0)

    KSTAGE(0, 0);
    __syncthreads();

    const f32x4 zero4 = {0.f, 0.f, 0.f, 0.f};
    f32x4 acc_o[4];
#pragma unroll
    for (int dj = 0; dj < 4; ++dj) acc_o[dj] = zero4;

    // per-lane stats for q-row = n0 + w*16 + l15 (identical across lg groups)
    float rmax = -3e38f, rsum = 0.f;

    const int qr = w * 16 + l15;
    bf16x8 aq[2];
#pragma unroll
    for (int kk = 0; kk < 2; ++kk)
        aq[kk] = *(const bf16x8*)&Qs[qr * 64 + (((kk * 4 + lg) ^ (qr & 7)) << 3)];

    const int qglob = n0 + w * 16 + l15;

    int cur = 0;
    for (int tile = 0; tile < 8; ++tile) {
        const int m0 = tile * 64;
        if (tile < 7) KSTAGE(cur ^ 1, m0 + 64);

        // swapped QK^T: s4[mi][reg] = S[m = m0 + mi*16 + lg*4 + reg][q = l15]
        f32x4 s4[4];
#pragma unroll
        for (int mi = 0; mi < 4; ++mi) s4[mi] = zero4;
#pragma unroll
        for (int kk = 0; kk < 2; ++kk) {
#pragma unroll
            for (int mi = 0; mi < 4; ++mi) {
                int mr = mi * 16 + l15;
                bf16x8 bk = *(const bf16x8*)&Ks[cur][mr * 64 + (((kk * 4 + lg) ^ (mr & 7)) << 3)];
                s4[mi] = __builtin_amdgcn_mfma_f32_16x16x32_bf16(bk, aq[kk], s4[mi], 0, 0, 0);
            }
        }

        // bias (log2 domain) + in-lane max
        const int ib = m0 + lg * 4 - qglob + 511;
        float tmax = -3e38f;
#pragma unroll
        for (int mi = 0; mi < 4; ++mi)
#pragma unroll
            for (int r = 0; r < 4; ++r) {
                float sv = s4[mi][r] * (0.125f * LOG2E_) + relh[ib + mi * 16 + r];
                s4[mi][r] = sv;
                tmax = fmaxf(tmax, sv);
            }
        tmax = fmaxf(tmax, __shfl_xor(tmax, 16));
        tmax = fmaxf(tmax, __shfl_xor(tmax, 32));

        // defer-max: rescale only when the new tile max exceeds rmax + 8
        if (!__all(tmax <= rmax + 8.f)) {
            float nm = fmaxf(rmax, tmax);
            float sc = __builtin_amdgcn_exp2f(rmax - nm);
            rmax = nm;
            rsum *= sc;
            float scl[4];
#pragma unroll
            for (int r = 0; r < 4; ++r)
                scl[r] = __shfl(sc, (lane & 48) | (lg * 4 + r));
#pragma unroll
            for (int dj = 0; dj < 4; ++dj)
#pragma unroll
                for (int r = 0; r < 4; ++r) acc_o[dj][r] *= scl[r];
        }

        // P = exp2(sv - rmax), in-lane sum
        float ts = 0.f;
#pragma unroll
        for (int mi = 0; mi < 4; ++mi)
#pragma unroll
            for (int r = 0; r < 4; ++r) {
                float p = __builtin_amdgcn_exp2f(s4[mi][r] - rmax);
                s4[mi][r] = p;
                ts += p;
            }
        ts += __shfl_xor(ts, 16);
        ts += __shfl_xor(ts, 32);
        rsum += ts;

        // pack P (m-consecutive pairs) and write to LDS, XOR-swizzled.
        // layout: Ps[w][q=l15][m], block(8 shorts) index ^= (q&7)
#pragma unroll
        for (int mi = 0; mi < 4; ++mi) {
            uint32_t w01 = cvt_pk_bf16(s4[mi][0], s4[mi][1]);
            uint32_t w23 = cvt_pk_bf16(s4[mi][2], s4[mi][3]);
            int blk = mi * 2 + (lg >> 1);
            int idx = w * 1024 + l15 * 64 + ((blk ^ (l15 & 7)) << 3) + ((lg & 1) << 2);
            *(uint2*)&Ps[idx] = make_uint2(w01, w23);
        }

        // PV: A = P (rows q at l15), B = V (rows d at l15)
#pragma unroll
        for (int kk = 0; kk < 2; ++kk) {
            bf16x8 ap = *(const bf16x8*)&Ps[w * 1024 + l15 * 64 + (((kk * 4 + lg) ^ (l15 & 7)) << 3)];
#pragma unroll
            for (int dj = 0; dj < 4; ++dj) {
                int dr = dj * 16 + l15;
                bf16x8 bv = *(const bf16x8*)&Vs[cur][dr * 64 + (((kk * 4 + lg) ^ (dr & 7)) << 3)];
                acc_o[dj] = __builtin_amdgcn_mfma_f32_16x16x32_bf16(ap, bv, acc_o[dj], 0, 0, 0);
            }
        }
        __syncthreads();            // drains prefetch before buffer swap
        cur ^= 1;
    }
#undef KSTAGE

    // redistribute 1/rsum from q=l15 lanes to q=lg*4+reg layout
    float inv = 1.f / rsum;
    float invr[4];
#pragma unroll
    for (int r = 0; r < 4; ++r)
        invr[r] = __shfl(inv, (lane & 48) | (lg * 4 + r));

    short* ob = attnT + (size_t)b * 512 * 512;
#pragma unroll
    for (int dj = 0; dj < 4; ++dj)
#pragma unroll
        for (int reg = 0; reg < 4; ++reg) {
            int nglob = n0 + w * 16 + lg * 4 + reg;
            ob[(size_t)nglob * 512 + h * 64 + dj * 16 + l15] =
                f2bf(acc_o[dj][reg] * invr[reg]);
        }
}

// ---------------------------------------------------------------------------
extern "C" void kernel_launch(void* const* d_in, const int* in_sizes, int n_in,
                              void* d_out, int out_size, void* d_ws, size_t ws_size,
                              hipStream_t stream)
{
    const float* x      = (const float*)d_in[0];
    const float* qkv_w  = (const float*)d_in[1];
    const float* qkv_b  = (const float*)d_in[2];
    const float* out_w  = (const float*)d_in[3];
    const float* out_b  = (const float*)d_in[4];
    const float* rel    = (const float*)d_in[5];
    const float* bn1_g  = (const float*)d_in[6];
    const float* bn1_b  = (const float*)d_in[7];
    const float* bn1_m  = (const float*)d_in[8];
    const float* bn1_v  = (const float*)d_in[9];
    const float* ffn1_w = (const float*)d_in[10];
    const float* ffn1_b = (const float*)d_in[11];
    const float* ffn2_w = (const float*)d_in[12];
    const float* ffn2_b = (const float*)d_in[13];
    const float* bn2_g  = (const float*)d_in[14];
    const float* bn2_b  = (const float*)d_in[15];
    const float* bn2_m  = (const float*)d_in[16];
    const float* bn2_v  = (const float*)d_in[17];

    float* out = (float*)d_out;
    short* ws  = (short*)d_ws;

    size_t off = 0;
    short* qkvw_bf = ws + off; off += (size_t)1536 * 512;   // cvt dest is
    short* outw_bf = ws + off; off += (size_t)512 * 512;    // contiguous
    short* f1w_bf  = ws + off; off += (size_t)1024 * 512;   // across these 4
    short* f2w_bf  = ws + off; off += (size_t)512 * 1024;
    short* xT      = ws + off; off += (size_t)B_ * 512 * 512;
    short* qkT     = ws + off; off += (size_t)B_ * 512 * 1024;
    short* vTb     = ws + off; off += (size_t)B_ * 512 * 512;
    short* attnT   = ws + off; off += (size_t)B_ * 512 * 512;
    short* h_bf    = ws + off; off += (size_t)B_ * 512 * 512;
    short* f1_bf   = ws + off; off += (size_t)B_ * 512 * 1024;

    const dim3 blk(256);

    // weight conversions (one launch, 524288 f32x4 groups)
    cvt_weights<<<dim3(524288 / 256), blk, 0, stream>>>(qkv_w, out_w, ffn1_w, ffn2_w, qkvw_bf);

    // x -> xT bf16 (also serves as BN1 residual, coalesced along c)
    transpose_x<<<dim3(8, 8, B_), blk, 0, stream>>>(x, xT);

    // 1) qkv projection (q,k -> qkT [n][1024]; v -> vTb [dv][n])
    gemm_mfma<EPI_QKV, 512, 1024><<<dim3(12, 4, B_), blk, 0, stream>>>(
        xT, qkvw_bf, qkv_b, qkT, vTb, nullptr, nullptr, nullptr, nullptr, nullptr, nullptr);

    // 2) attention (1-D grid, XCD-affine decode)
    attn_mfma<<<dim3(2048), blk, 0, stream>>>(qkT, vTb, rel, attnT);

    // 3) out projection + residual(xT) + BN1 -> h_bf
    gemm_mfma<EPI_BN1, 512, 512><<<dim3(4, 4, B_), blk, 0, stream>>>(
        attnT, outw_bf, out_b, h_bf, nullptr, nullptr, xT, bn1_g, bn1_b, bn1_m, bn1_v);

    // 4) ffn1 + GELU -> f1_bf
    gemm_mfma<EPI_GELU, 512, 1024><<<dim3(8, 4, B_), blk, 0, stream>>>(
        h_bf, f1w_bf, ffn1_b, f1_bf, nullptr, nullptr, nullptr, nullptr, nullptr, nullptr, nullptr);

    // 5) ffn2 + residual(h_bf) + BN2 -> out fp32 [b][c][n]
    gemm_mfma<EPI_BN2, 1024, 512><<<dim3(4, 4, B_), blk, 0, stream>>>(
        f1_bf, f2w_bf, ffn2_b, nullptr, nullptr, out, h_bf, bn2_g, bn2_b, bn2_m, bn2_v);
}

// Round 9
// 194.553 us; speedup vs baseline: 1.2920x; 1.1224x over previous
//
#include <hip/hip_runtime.h>
#include <cstddef>
#include <cstdint>

constexpr int B_ = 32;
constexpr int C_ = 512;
constexpr int N_ = 512;
constexpr int H_ = 8;
constexpr int FH_ = 1024;
constexpr float BN_EPS_ = 1e-5f;
constexpr float LOG2E_ = 1.44269504088896f;

typedef __attribute__((ext_vector_type(8))) short bf16x8;
typedef __attribute__((ext_vector_type(4))) short s16x4;
typedef __attribute__((ext_vector_type(4))) float f32x4;

enum { EPI_QKV = 0, EPI_BN1 = 1, EPI_GELU = 2, EPI_BN2 = 3 };

__device__ inline void gload_lds16(const void* g, void* l) {
    __builtin_amdgcn_global_load_lds(
        (const __attribute__((address_space(1))) void*)g,
        (__attribute__((address_space(3))) void*)l, 16, 0, 0);
}

__device__ inline short f2bf(float f) {
    union { float f; uint32_t u; } v; v.f = f;
    uint32_t r = v.u + 0x7fffu + ((v.u >> 16) & 1u);
    return (short)(r >> 16);
}

__device__ inline float bf2f(short s) {
    union { uint32_t u; float f; } v;
    v.u = ((uint32_t)(uint16_t)s) << 16;
    return v.f;
}

__device__ inline uint32_t cvt_pk_bf16(float lo, float hi) {
    uint32_t r;
    asm("v_cvt_pk_bf16_f32 %0, %1, %2" : "=v"(r) : "v"(lo), "v"(hi));
    return r;
}

// ---------------------------------------------------------------------------
// all four weight matrices fp32 -> bf16 in one launch (dest contiguous in ws)
// ---------------------------------------------------------------------------
__global__ __launch_bounds__(256) void cvt_weights(
    const float* __restrict__ s0, const float* __restrict__ s1,
    const float* __restrict__ s2, const float* __restrict__ s3,
    short* __restrict__ d)
{
    int i = blockIdx.x * 256 + threadIdx.x;
    const float* src;
    int local;
    if (i < 196608)      { src = s0; local = i; }
    else if (i < 262144) { src = s1; local = i - 196608; }
    else if (i < 393216) { src = s2; local = i - 262144; }
    else                 { src = s3; local = i - 393216; }
    f32x4 v = *(const f32x4*)&src[(size_t)local * 4];
    s16x4 o;
    o[0] = f2bf(v[0]); o[1] = f2bf(v[1]); o[2] = f2bf(v[2]); o[3] = f2bf(v[3]);
    *(s16x4*)&d[(size_t)i * 4] = o;
}

// ---------------------------------------------------------------------------
// x [B][C][N] fp32 -> xT [B][N][C] bf16
// ---------------------------------------------------------------------------
__global__ __launch_bounds__(256) void transpose_x(const float* __restrict__ x,
                                                   short* __restrict__ xT)
{
    __shared__ __align__(16) float s[64][65];
    const int b = blockIdx.z, c0 = blockIdx.x * 64, n0 = blockIdx.y * 64;
    const int t = threadIdx.x;
    const float* xb = x + ((size_t)b * C_ + c0) * N_ + n0;
    {
        int nl = t & 63, cl = t >> 6;
#pragma unroll
        for (int i = 0; i < 16; ++i)
            s[cl + i * 4][nl] = xb[(size_t)(cl + i * 4) * N_ + nl];
    }
    __syncthreads();
    short* xTb = xT + ((size_t)b * N_ + n0) * C_ + c0;
    {
        int cl = t & 63, nl = t >> 6;
#pragma unroll
        for (int i = 0; i < 16; ++i)
            xTb[(size_t)(nl + i * 4) * C_ + cl] = f2bf(s[cl][nl + i * 4]);
    }
}

// ---------------------------------------------------------------------------
// MFMA GEMM: Y[b][n][o] = sum_c A[b][n][c] * W[o][c]  (+ epilogue)
// 128x128 tile, BK=32, 256 threads (4 waves, 2x2), 16x16x32 bf16 MFMA.
// T4 counted-vmcnt pipeline: 4 LDS buffers, prefetch distance 2, one
// s_barrier per K-step preceded by s_waitcnt vmcnt(4) (vmcnt(0) only at
// the last step). Source k-block XOR'd, same XOR on ds_read (involution,
// correctness-neutral).
// ---------------------------------------------------------------------------
template <int EPI, int KD, int OSTR>
__global__ __launch_bounds__(256) void gemm_mfma(
    const short* __restrict__ A, const short* __restrict__ W,
    const float* __restrict__ bias,
    short* __restrict__ Yb, short* __restrict__ Yv, float* __restrict__ Yf,
    const short* __restrict__ resb,
    const float* __restrict__ g, const float* __restrict__ bt,
    const float* __restrict__ mn, const float* __restrict__ vr)
{
    const int b  = blockIdx.z;
    const int o0 = blockIdx.x * 128;
    const int n0 = blockIdx.y * 128;
    const short* Ab = A + (size_t)b * 512 * KD;

    __shared__ __align__(16) short As[4][128 * 32];
    __shared__ __align__(16) short Bs[4][128 * 32];

    const int t = threadIdx.x;
    const int lane = t & 63, w = t >> 6;
    const int l15 = lane & 15, lg = lane >> 4;
    const int wr = w >> 1, wc = w & 1;

    const f32x4 zero4 = {0.f, 0.f, 0.f, 0.f};
    f32x4 acc[4][4];
#pragma unroll
    for (int i = 0; i < 4; ++i)
#pragma unroll
        for (int j = 0; j < 4; ++j) acc[i][j] = zero4;

    const int r0 = t >> 2;                              // staging row (0..63)
    const int kb = (((t & 3) ^ ((t >> 3) & 3)) * 8);    // swizzled source k-block

    constexpr int Kt = KD / 32;

#define GSTAGE(bufi, kk0)                                                        \
    do {                                                                         \
        gload_lds16(Ab + (size_t)(n0 + r0) * KD + (kk0) + kb,      &As[bufi][w * 512]);        \
        gload_lds16(Ab + (size_t)(n0 + r0 + 64) * KD + (kk0) + kb, &As[bufi][w * 512 + 2048]); \
        gload_lds16(W  + (size_t)(o0 + r0) * KD + (kk0) + kb,      &Bs[bufi][w * 512]);        \
        gload_lds16(W  + (size_t)(o0 + r0 + 64) * KD + (kk0) + kb, &Bs[bufi][w * 512 + 2048]); \
    } while (0)

    GSTAGE(0, 0);
    GSTAGE(1, 32);

    const int rsw = (lg ^ ((l15 >> 1) & 3)) * 8;        // swizzled read offset

    for (int kt = 0; kt < Kt; kt += 4) {
#pragma unroll
        for (int u = 0; u < 4; ++u) {
            const int k = kt + u;
            if (k == Kt - 1) asm volatile("s_waitcnt vmcnt(0)" ::: "memory");
            else             asm volatile("s_waitcnt vmcnt(4)" ::: "memory");
            __builtin_amdgcn_s_barrier();
            __builtin_amdgcn_sched_barrier(0);
            if (k + 2 < Kt) GSTAGE((u + 2) & 3, (k + 2) * 32);

            bf16x8 af[4], bf[4];
#pragma unroll
            for (int mi = 0; mi < 4; ++mi)
                af[mi] = *(const bf16x8*)&As[u][(wr * 64 + mi * 16 + l15) * 32 + rsw];
#pragma unroll
            for (int ni = 0; ni < 4; ++ni)
                bf[ni] = *(const bf16x8*)&Bs[u][(wc * 64 + ni * 16 + l15) * 32 + rsw];
#pragma unroll
            for (int mi = 0; mi < 4; ++mi)
#pragma unroll
                for (int ni = 0; ni < 4; ++ni)
                    acc[mi][ni] = __builtin_amdgcn_mfma_f32_16x16x32_bf16(
                        af[mi], bf[ni], acc[mi][ni], 0, 0, 0);
        }
    }
#undef GSTAGE

    // epilogue
#pragma unroll
    for (int mi = 0; mi < 4; ++mi) {
        const int nb = n0 + wr * 64 + mi * 16 + lg * 4;   // rows nb..nb+3
#pragma unroll
        for (int ni = 0; ni < 4; ++ni) {
            const int o = o0 + wc * 64 + ni * 16 + l15;
            const float bv = bias[o];
            f32x4 v = acc[mi][ni];
            if constexpr (EPI == EPI_QKV) {
                if (o0 < 1024) {
#pragma unroll
                    for (int r = 0; r < 4; ++r)
                        Yb[((size_t)b * 512 + nb + r) * 1024 + o] = f2bf(v[r] + bv);
                } else {
                    s16x4 pk;
#pragma unroll
                    for (int r = 0; r < 4; ++r) pk[r] = f2bf(v[r] + bv);
                    *(s16x4*)&Yv[((size_t)b * 512 + (o - 1024)) * 512 + nb] = pk;
                }
            } else if constexpr (EPI == EPI_BN1) {
                const float sc = g[o] * rsqrtf(vr[o] + BN_EPS_);
                const float sh = bt[o] - mn[o] * sc;
#pragma unroll
                for (int r = 0; r < 4; ++r) {
                    float rr = bf2f(resb[((size_t)b * 512 + nb + r) * 512 + o]);
                    float val = (v[r] + bv + rr) * sc + sh;
                    Yb[((size_t)b * 512 + nb + r) * 512 + o] = f2bf(val);
                }
            } else if constexpr (EPI == EPI_GELU) {
#pragma unroll
                for (int r = 0; r < 4; ++r) {
                    float val = v[r] + bv;
                    val = 0.5f * val * (1.0f + erff(val * 0.70710678118654752f));
                    Yb[((size_t)b * 512 + nb + r) * OSTR + o] = f2bf(val);
                }
            } else { // EPI_BN2 -> final fp32 out [b][o][n], residual h_bf
                const float sc = g[o] * rsqrtf(vr[o] + BN_EPS_);
                const float sh = bt[o] - mn[o] * sc;
                f32x4 ov;
#pragma unroll
                for (int r = 0; r < 4; ++r) {
                    float hres = bf2f(resb[((size_t)b * 512 + nb + r) * 512 + o]);
                    ov[r] = (v[r] + bv + hres) * sc + sh;
                }
                *(f32x4*)&Yf[((size_t)b * 512 + o) * 512 + nb] = ov;
            }
        }
    }
}

// ---------------------------------------------------------------------------
// Attention (flash-style, MFMA, SWAPPED QK^T). Block: (b, h, 64 q-rows).
// s = mfma(K_frag, Q_frag) -> S[m at lg*4+reg (+16*mi)][q at l15]:
// each lane owns ONE q-row -> softmax reduce = in-lane + 2 shfl_xor.
// Defer-max (THR=8 in log2 domain). P packed via v_cvt_pk_bf16_f32,
// 4x ds_write_b64 (XOR-swizzled), PV A-frag read matches GEMM layout.
// Grid 2048 1-D: h = id&7 (XCD affinity), n0 = ((id>>3)&7)*64, b = id>>6.
// ---------------------------------------------------------------------------
__global__ __launch_bounds__(256) void attn_mfma(
    const short* __restrict__ qkT, const short* __restrict__ vT,
    const float* __restrict__ rel, short* __restrict__ attnT)
{
    const int id = blockIdx.x;
    const int h  = id & 7;
    const int n0 = ((id >> 3) & 7) * 64;
    const int b  = id >> 6;
    const int t  = threadIdx.x;
    const int lane = t & 63, w = t >> 6;
    const int l15 = lane & 15, lg = lane >> 4;

    __shared__ __align__(16) short Qs[64 * 64];
    __shared__ __align__(16) short Ks[2][64 * 64];
    __shared__ __align__(16) short Vs[2][64 * 64];
    __shared__ __align__(16) short Ps[4 * 16 * 64];
    __shared__ __align__(16) float relh[1024];

    const short* qb = qkT + (size_t)b * 512 * 1024;
    const short* vb = vT + (size_t)b * 512 * 512;

    for (int i = t; i < 1023; i += 256) relh[i] = rel[i * H_ + h] * LOG2E_;

    // stage Q [64 r][64 d] (swizzled 16B blocks within each row)
#pragma unroll
    for (int i = 0; i < 2; ++i) {
        int fl = t * 8 + i * 2048;
        int r = fl >> 6;
        int blk = (fl >> 3) & 7;
        int d = ((blk ^ (r & 7)) << 3);
        gload_lds16(qb + (size_t)(n0 + r) * 1024 + h * 64 + d, &Qs[w * 512 + i * 2048]);
    }

#define KSTAGE(bufi, m0s)                                                        \
    do {                                                                         \
        _Pragma("unroll")                                                        \
        for (int i_ = 0; i_ < 2; ++i_) {                                         \
            int fl_ = t * 8 + i_ * 2048;                                         \
            int r_ = fl_ >> 6;                                                   \
            int blk_ = (fl_ >> 3) & 7;                                           \
            int d_ = ((blk_ ^ (r_ & 7)) << 3);                                   \
            gload_lds16(qb + (size_t)((m0s) + r_) * 1024 + 512 + h * 64 + d_,    \
                        &Ks[bufi][w * 512 + i_ * 2048]);                         \
        }                                                                        \
        _Pragma("unroll")                                                        \
        for (int i_ = 0; i_ < 2; ++i_) {                                         \
            int fl_ = t * 8 + i_ * 2048;                                         \
            int dr_ = fl_ >> 6;                                                  \
            int blk_ = (fl_ >> 3) & 7;                                           \
            int m_ = ((blk_ ^ (dr_ & 7)) << 3);                                  \
            gload_lds16(vb + (size_t)(h * 64 + dr_) * 512 + (m0s) + m_,          \
                        &Vs[bufi][w * 512 + i_ * 2048]);                         \
        }                                                                        \
    } while (0)

    KSTAGE(0, 0);
    __syncthreads();

    const f32x4 zero4 = {0.f, 0.f, 0.f, 0.f};
    f32x4 acc_o[4];
#pragma unroll
    for (int dj = 0; dj < 4; ++dj) acc_o[dj] = zero4;

    // per-lane stats for q-row = n0 + w*16 + l15 (identical across lg groups)
    float rmax = -3e38f, rsum = 0.f;

    const int qr = w * 16 + l15;
    bf16x8 aq[2];
#pragma unroll
    for (int kk = 0; kk < 2; ++kk)
        aq[kk] = *(const bf16x8*)&Qs[qr * 64 + (((kk * 4 + lg) ^ (qr & 7)) << 3)];

    const int qglob = n0 + w * 16 + l15;

    int cur = 0;
    for (int tile = 0; tile < 8; ++tile) {
        const int m0 = tile * 64;
        if (tile < 7) KSTAGE(cur ^ 1, m0 + 64);

        // swapped QK^T: s4[mi][reg] = S[m = m0 + mi*16 + lg*4 + reg][q = l15]
        f32x4 s4[4];
#pragma unroll
        for (int mi = 0; mi < 4; ++mi) s4[mi] = zero4;
#pragma unroll
        for (int kk = 0; kk < 2; ++kk) {
#pragma unroll
            for (int mi = 0; mi < 4; ++mi) {
                int mr = mi * 16 + l15;
                bf16x8 bk = *(const bf16x8*)&Ks[cur][mr * 64 + (((kk * 4 + lg) ^ (mr & 7)) << 3)];
                s4[mi] = __builtin_amdgcn_mfma_f32_16x16x32_bf16(bk, aq[kk], s4[mi], 0, 0, 0);
            }
        }

        // bias (log2 domain) + in-lane max
        const int ib = m0 + lg * 4 - qglob + 511;
        float tmax = -3e38f;
#pragma unroll
        for (int mi = 0; mi < 4; ++mi)
#pragma unroll
            for (int r = 0; r < 4; ++r) {
                float sv = s4[mi][r] * (0.125f * LOG2E_) + relh[ib + mi * 16 + r];
                s4[mi][r] = sv;
                tmax = fmaxf(tmax, sv);
            }
        tmax = fmaxf(tmax, __shfl_xor(tmax, 16));
        tmax = fmaxf(tmax, __shfl_xor(tmax, 32));

        // defer-max: rescale only when the new tile max exceeds rmax + 8
        if (!__all(tmax <= rmax + 8.f)) {
            float nm = fmaxf(rmax, tmax);
            float sc = __builtin_amdgcn_exp2f(rmax - nm);
            rmax = nm;
            rsum *= sc;
            float scl[4];
#pragma unroll
            for (int r = 0; r < 4; ++r)
                scl[r] = __shfl(sc, (lane & 48) | (lg * 4 + r));
#pragma unroll
            for (int dj = 0; dj < 4; ++dj)
#pragma unroll
                for (int r = 0; r < 4; ++r) acc_o[dj][r] *= scl[r];
        }

        // P = exp2(sv - rmax), in-lane sum
        float ts = 0.f;
#pragma unroll
        for (int mi = 0; mi < 4; ++mi)
#pragma unroll
            for (int r = 0; r < 4; ++r) {
                float p = __builtin_amdgcn_exp2f(s4[mi][r] - rmax);
                s4[mi][r] = p;
                ts += p;
            }
        ts += __shfl_xor(ts, 16);
        ts += __shfl_xor(ts, 32);
        rsum += ts;

        // pack P (m-consecutive pairs) and write to LDS, XOR-swizzled.
        // layout: Ps[w][q=l15][m], block(8 shorts) index ^= (q&7)
#pragma unroll
        for (int mi = 0; mi < 4; ++mi) {
            uint32_t w01 = cvt_pk_bf16(s4[mi][0], s4[mi][1]);
            uint32_t w23 = cvt_pk_bf16(s4[mi][2], s4[mi][3]);
            int blk = mi * 2 + (lg >> 1);
            int idx = w * 1024 + l15 * 64 + ((blk ^ (l15 & 7)) << 3) + ((lg & 1) << 2);
            *(uint2*)&Ps[idx] = make_uint2(w01, w23);
        }

        // PV: A = P (rows q at l15), B = V (rows d at l15)
#pragma unroll
        for (int kk = 0; kk < 2; ++kk) {
            bf16x8 ap = *(const bf16x8*)&Ps[w * 1024 + l15 * 64 + (((kk * 4 + lg) ^ (l15 & 7)) << 3)];
#pragma unroll
            for (int dj = 0; dj < 4; ++dj) {
                int dr = dj * 16 + l15;
                bf16x8 bv = *(const bf16x8*)&Vs[cur][dr * 64 + (((kk * 4 + lg) ^ (dr & 7)) << 3)];
                acc_o[dj] = __builtin_amdgcn_mfma_f32_16x16x32_bf16(ap, bv, acc_o[dj], 0, 0, 0);
            }
        }
        __syncthreads();            // drains prefetch before buffer swap
        cur ^= 1;
    }
#undef KSTAGE

    // redistribute 1/rsum from q=l15 lanes to q=lg*4+reg layout
    float inv = 1.f / rsum;
    float invr[4];
#pragma unroll
    for (int r = 0; r < 4; ++r)
        invr[r] = __shfl(inv, (lane & 48) | (lg * 4 + r));

    short* ob = attnT + (size_t)b * 512 * 512;
#pragma unroll
    for (int dj = 0; dj < 4; ++dj)
#pragma unroll
        for (int reg = 0; reg < 4; ++reg) {
            int nglob = n0 + w * 16 + lg * 4 + reg;
            ob[(size_t)nglob * 512 + h * 64 + dj * 16 + l15] =
                f2bf(acc_o[dj][reg] * invr[reg]);
        }
}

// ---------------------------------------------------------------------------
extern "C" void kernel_launch(void* const* d_in, const int* in_sizes, int n_in,
                              void* d_out, int out_size, void* d_ws, size_t ws_size,
                              hipStream_t stream)
{
    const float* x      = (const float*)d_in[0];
    const float* qkv_w  = (const float*)d_in[1];
    const float* qkv_b  = (const float*)d_in[2];
    const float* out_w  = (const float*)d_in[3];
    const float* out_b  = (const float*)d_in[4];
    const float* rel    = (const float*)d_in[5];
    const float* bn1_g  = (const float*)d_in[6];
    const float* bn1_b  = (const float*)d_in[7];
    const float* bn1_m  = (const float*)d_in[8];
    const float* bn1_v  = (const float*)d_in[9];
    const float* ffn1_w = (const float*)d_in[10];
    const float* ffn1_b = (const float*)d_in[11];
    const float* ffn2_w = (const float*)d_in[12];
    const float* ffn2_b = (const float*)d_in[13];
    const float* bn2_g  = (const float*)d_in[14];
    const float* bn2_b  = (const float*)d_in[15];
    const float* bn2_m  = (const float*)d_in[16];
    const float* bn2_v  = (const float*)d_in[17];

    float* out = (float*)d_out;
    short* ws  = (short*)d_ws;

    size_t off = 0;
    short* qkvw_bf = ws + off; off += (size_t)1536 * 512;   // cvt dest is
    short* outw_bf = ws + off; off += (size_t)512 * 512;    // contiguous
    short* f1w_bf  = ws + off; off += (size_t)1024 * 512;   // across these 4
    short* f2w_bf  = ws + off; off += (size_t)512 * 1024;
    short* xT      = ws + off; off += (size_t)B_ * 512 * 512;
    short* qkT     = ws + off; off += (size_t)B_ * 512 * 1024;
    short* vTb     = ws + off; off += (size_t)B_ * 512 * 512;
    short* attnT   = ws + off; off += (size_t)B_ * 512 * 512;
    short* h_bf    = ws + off; off += (size_t)B_ * 512 * 512;
    short* f1_bf   = ws + off; off += (size_t)B_ * 512 * 1024;

    const dim3 blk(256);

    // weight conversions (one launch, 524288 f32x4 groups)
    cvt_weights<<<dim3(524288 / 256), blk, 0, stream>>>(qkv_w, out_w, ffn1_w, ffn2_w, qkvw_bf);

    // x -> xT bf16 (also serves as BN1 residual, coalesced along c)
    transpose_x<<<dim3(8, 8, B_), blk, 0, stream>>>(x, xT);

    // 1) qkv projection (q,k -> qkT [n][1024]; v -> vTb [dv][n])
    gemm_mfma<EPI_QKV, 512, 1024><<<dim3(12, 4, B_), blk, 0, stream>>>(
        xT, qkvw_bf, qkv_b, qkT, vTb, nullptr, nullptr, nullptr, nullptr, nullptr, nullptr);

    // 2) attention (1-D grid, XCD-affine decode)
    attn_mfma<<<dim3(2048), blk, 0, stream>>>(qkT, vTb, rel, attnT);

    // 3) out projection + residual(xT) + BN1 -> h_bf
    gemm_mfma<EPI_BN1, 512, 512><<<dim3(4, 4, B_), blk, 0, stream>>>(
        attnT, outw_bf, out_b, h_bf, nullptr, nullptr, xT, bn1_g, bn1_b, bn1_m, bn1_v);

    // 4) ffn1 + GELU -> f1_bf
    gemm_mfma<EPI_GELU, 512, 1024><<<dim3(8, 4, B_), blk, 0, stream>>>(
        h_bf, f1w_bf, ffn1_b, f1_bf, nullptr, nullptr, nullptr, nullptr, nullptr, nullptr, nullptr);

    // 5) ffn2 + residual(h_bf) + BN2 -> out fp32 [b][c][n]
    gemm_mfma<EPI_BN2, 1024, 512><<<dim3(4, 4, B_), blk, 0, stream>>>(
        f1_bf, f2w_bf, ffn2_b, nullptr, nullptr, out, h_bf, bn2_g, bn2_b, bn2_m, bn2_v);
}

// Round 10
// 180.050 us; speedup vs baseline: 1.3961x; 1.0806x over previous
//
#include <hip/hip_runtime.h>
#include <cstddef>
#include <cstdint>

constexpr int B_ = 32;
constexpr int C_ = 512;
constexpr int N_ = 512;
constexpr int H_ = 8;
constexpr int FH_ = 1024;
constexpr float BN_EPS_ = 1e-5f;
constexpr float LOG2E_ = 1.44269504088896f;

typedef __attribute__((ext_vector_type(8))) short bf16x8;
typedef __attribute__((ext_vector_type(4))) short s16x4;
typedef __attribute__((ext_vector_type(4))) float f32x4;

enum { EPI_QKV = 0, EPI_BN1 = 1, EPI_GELU = 2, EPI_BN2 = 3 };

__device__ inline void gload_lds16(const void* g, void* l) {
    __builtin_amdgcn_global_load_lds(
        (const __attribute__((address_space(1))) void*)g,
        (__attribute__((address_space(3))) void*)l, 16, 0, 0);
}

__device__ inline short f2bf(float f) {
    union { float f; uint32_t u; } v; v.f = f;
    uint32_t r = v.u + 0x7fffu + ((v.u >> 16) & 1u);
    return (short)(r >> 16);
}

__device__ inline float bf2f(short s) {
    union { uint32_t u; float f; } v;
    v.u = ((uint32_t)(uint16_t)s) << 16;
    return v.f;
}

__device__ inline uint32_t cvt_pk_bf16(float lo, float hi) {
    uint32_t r;
    asm("v_cvt_pk_bf16_f32 %0, %1, %2" : "=v"(r) : "v"(lo), "v"(hi));
    return r;
}

// ---------------------------------------------------------------------------
// all four weight matrices fp32 -> bf16 in one launch (dest contiguous in ws)
// ---------------------------------------------------------------------------
__global__ __launch_bounds__(256) void cvt_weights(
    const float* __restrict__ s0, const float* __restrict__ s1,
    const float* __restrict__ s2, const float* __restrict__ s3,
    short* __restrict__ d)
{
    int i = blockIdx.x * 256 + threadIdx.x;
    const float* src;
    int local;
    if (i < 196608)      { src = s0; local = i; }
    else if (i < 262144) { src = s1; local = i - 196608; }
    else if (i < 393216) { src = s2; local = i - 262144; }
    else                 { src = s3; local = i - 393216; }
    f32x4 v = *(const f32x4*)&src[(size_t)local * 4];
    s16x4 o;
    o[0] = f2bf(v[0]); o[1] = f2bf(v[1]); o[2] = f2bf(v[2]); o[3] = f2bf(v[3]);
    *(s16x4*)&d[(size_t)i * 4] = o;
}

// ---------------------------------------------------------------------------
// x [B][C][N] fp32 -> xT [B][N][C] bf16
// ---------------------------------------------------------------------------
__global__ __launch_bounds__(256) void transpose_x(const float* __restrict__ x,
                                                   short* __restrict__ xT)
{
    __shared__ __align__(16) float s[64][65];
    const int b = blockIdx.z, c0 = blockIdx.x * 64, n0 = blockIdx.y * 64;
    const int t = threadIdx.x;
    const float* xb = x + ((size_t)b * C_ + c0) * N_ + n0;
    {
        int nl = t & 63, cl = t >> 6;
#pragma unroll
        for (int i = 0; i < 16; ++i)
            s[cl + i * 4][nl] = xb[(size_t)(cl + i * 4) * N_ + nl];
    }
    __syncthreads();
    short* xTb = xT + ((size_t)b * N_ + n0) * C_ + c0;
    {
        int cl = t & 63, nl = t >> 6;
#pragma unroll
        for (int i = 0; i < 16; ++i)
            xTb[(size_t)(nl + i * 4) * C_ + cl] = f2bf(s[cl][nl + i * 4]);
    }
}

// ---------------------------------------------------------------------------
// MFMA GEMM: Y[b][n][o] = sum_c A[b][n][c] * W[o][c]  (+ epilogue)
// 128x128 tile, BK=32, 256 threads (4 waves, 2x2), 16x16x32 bf16 MFMA.
// T4 counted-vmcnt pipeline (4 LDS buffers, distance 2, vmcnt(4) per step).
// T1 XCD-chunked 1-D grid: swz = (bid&7)*(nwg/8) + bid>>3, decoded o-fastest
// so one XCD consumes all o-tiles of an A-slice back-to-back (L2-resident).
// ---------------------------------------------------------------------------
template <int EPI, int KD, int OSTR, int OB, int NB>
__global__ __launch_bounds__(256) void gemm_mfma(
    const short* __restrict__ A, const short* __restrict__ W,
    const float* __restrict__ bias,
    short* __restrict__ Yb, short* __restrict__ Yv, float* __restrict__ Yf,
    const short* __restrict__ resb,
    const float* __restrict__ g, const float* __restrict__ bt,
    const float* __restrict__ mn, const float* __restrict__ vr)
{
    constexpr int NWG = OB * NB * B_;
    constexpr int CPX = NWG / 8;
    const int bid = blockIdx.x;
    const int swz = (bid & 7) * CPX + (bid >> 3);
    const int ob  = swz % OB;
    const int rst = swz / OB;
    const int b   = rst / NB;
    const int o0  = ob * 128;
    const int n0  = (rst % NB) * 128;
    const short* Ab = A + (size_t)b * 512 * KD;

    __shared__ __align__(16) short As[4][128 * 32];
    __shared__ __align__(16) short Bs[4][128 * 32];

    const int t = threadIdx.x;
    const int lane = t & 63, w = t >> 6;
    const int l15 = lane & 15, lg = lane >> 4;
    const int wr = w >> 1, wc = w & 1;

    const f32x4 zero4 = {0.f, 0.f, 0.f, 0.f};
    f32x4 acc[4][4];
#pragma unroll
    for (int i = 0; i < 4; ++i)
#pragma unroll
        for (int j = 0; j < 4; ++j) acc[i][j] = zero4;

    const int r0 = t >> 2;                              // staging row (0..63)
    const int kb = (((t & 3) ^ ((t >> 3) & 3)) * 8);    // swizzled source k-block

    constexpr int Kt = KD / 32;

#define GSTAGE(bufi, kk0)                                                        \
    do {                                                                         \
        gload_lds16(Ab + (size_t)(n0 + r0) * KD + (kk0) + kb,      &As[bufi][w * 512]);        \
        gload_lds16(Ab + (size_t)(n0 + r0 + 64) * KD + (kk0) + kb, &As[bufi][w * 512 + 2048]); \
        gload_lds16(W  + (size_t)(o0 + r0) * KD + (kk0) + kb,      &Bs[bufi][w * 512]);        \
        gload_lds16(W  + (size_t)(o0 + r0 + 64) * KD + (kk0) + kb, &Bs[bufi][w * 512 + 2048]); \
    } while (0)

    GSTAGE(0, 0);
    GSTAGE(1, 32);

    const int rsw = (lg ^ ((l15 >> 1) & 3)) * 8;        // swizzled read offset

    for (int kt = 0; kt < Kt; kt += 4) {
#pragma unroll
        for (int u = 0; u < 4; ++u) {
            const int k = kt + u;
            if (k == Kt - 1) asm volatile("s_waitcnt vmcnt(0)" ::: "memory");
            else             asm volatile("s_waitcnt vmcnt(4)" ::: "memory");
            __builtin_amdgcn_s_barrier();
            __builtin_amdgcn_sched_barrier(0);
            if (k + 2 < Kt) GSTAGE((u + 2) & 3, (k + 2) * 32);

            bf16x8 af[4], bf[4];
#pragma unroll
            for (int mi = 0; mi < 4; ++mi)
                af[mi] = *(const bf16x8*)&As[u][(wr * 64 + mi * 16 + l15) * 32 + rsw];
#pragma unroll
            for (int ni = 0; ni < 4; ++ni)
                bf[ni] = *(const bf16x8*)&Bs[u][(wc * 64 + ni * 16 + l15) * 32 + rsw];
#pragma unroll
            for (int mi = 0; mi < 4; ++mi)
#pragma unroll
                for (int ni = 0; ni < 4; ++ni)
                    acc[mi][ni] = __builtin_amdgcn_mfma_f32_16x16x32_bf16(
                        af[mi], bf[ni], acc[mi][ni], 0, 0, 0);
        }
    }
#undef GSTAGE

    // epilogue
#pragma unroll
    for (int mi = 0; mi < 4; ++mi) {
        const int nb2 = n0 + wr * 64 + mi * 16 + lg * 4;   // rows nb2..nb2+3
#pragma unroll
        for (int ni = 0; ni < 4; ++ni) {
            const int o = o0 + wc * 64 + ni * 16 + l15;
            const float bv = bias[o];
            f32x4 v = acc[mi][ni];
            if constexpr (EPI == EPI_QKV) {
                if (o0 < 1024) {
#pragma unroll
                    for (int r = 0; r < 4; ++r)
                        Yb[((size_t)b * 512 + nb2 + r) * 1024 + o] = f2bf(v[r] + bv);
                } else {
                    s16x4 pk;
#pragma unroll
                    for (int r = 0; r < 4; ++r) pk[r] = f2bf(v[r] + bv);
                    *(s16x4*)&Yv[((size_t)b * 512 + (o - 1024)) * 512 + nb2] = pk;
                }
            } else if constexpr (EPI == EPI_BN1) {
                const float sc = g[o] * rsqrtf(vr[o] + BN_EPS_);
                const float sh = bt[o] - mn[o] * sc;
#pragma unroll
                for (int r = 0; r < 4; ++r) {
                    float rr = bf2f(resb[((size_t)b * 512 + nb2 + r) * 512 + o]);
                    float val = (v[r] + bv + rr) * sc + sh;
                    Yb[((size_t)b * 512 + nb2 + r) * 512 + o] = f2bf(val);
                }
            } else if constexpr (EPI == EPI_GELU) {
#pragma unroll
                for (int r = 0; r < 4; ++r) {
                    float val = v[r] + bv;
                    val = 0.5f * val * (1.0f + erff(val * 0.70710678118654752f));
                    Yb[((size_t)b * 512 + nb2 + r) * OSTR + o] = f2bf(val);
                }
            } else { // EPI_BN2 -> final fp32 out [b][o][n], residual h_bf
                const float sc = g[o] * rsqrtf(vr[o] + BN_EPS_);
                const float sh = bt[o] - mn[o] * sc;
                f32x4 ov;
#pragma unroll
                for (int r = 0; r < 4; ++r) {
                    float hres = bf2f(resb[((size_t)b * 512 + nb2 + r) * 512 + o]);
                    ov[r] = (v[r] + bv + hres) * sc + sh;
                }
                *(f32x4*)&Yf[((size_t)b * 512 + o) * 512 + nb2] = ov;
            }
        }
    }
}

// ---------------------------------------------------------------------------
// Attention (flash-style, MFMA, SWAPPED QK^T). Block: (b, h, 64 q-rows).
// Grid 2048 1-D: h = id&7 (XCD affinity), n0 = ((id>>3)&7)*64, b = id>>6.
// ---------------------------------------------------------------------------
__global__ __launch_bounds__(256) void attn_mfma(
    const short* __restrict__ qkT, const short* __restrict__ vT,
    const float* __restrict__ rel, short* __restrict__ attnT)
{
    const int id = blockIdx.x;
    const int h  = id & 7;
    const int n0 = ((id >> 3) & 7) * 64;
    const int b  = id >> 6;
    const int t  = threadIdx.x;
    const int lane = t & 63, w = t >> 6;
    const int l15 = lane & 15, lg = lane >> 4;

    __shared__ __align__(16) short Qs[64 * 64];
    __shared__ __align__(16) short Ks[2][64 * 64];
    __shared__ __align__(16) short Vs[2][64 * 64];
    __shared__ __align__(16) short Ps[4 * 16 * 64];
    __shared__ __align__(16) float relh[1024];

    const short* qb = qkT + (size_t)b * 512 * 1024;
    const short* vb = vT + (size_t)b * 512 * 512;

    for (int i = t; i < 1023; i += 256) relh[i] = rel[i * H_ + h] * LOG2E_;

    // stage Q [64 r][64 d] (swizzled 16B blocks within each row)
#pragma unroll
    for (int i = 0; i < 2; ++i) {
        int fl = t * 8 + i * 2048;
        int r = fl >> 6;
        int blk = (fl >> 3) & 7;
        int d = ((blk ^ (r & 7)) << 3);
        gload_lds16(qb + (size_t)(n0 + r) * 1024 + h * 64 + d, &Qs[w * 512 + i * 2048]);
    }

#define KSTAGE(bufi, m0s)                                                        \
    do {                                                                         \
        _Pragma("unroll")                                                        \
        for (int i_ = 0; i_ < 2; ++i_) {                                         \
            int fl_ = t * 8 + i_ * 2048;                                         \
            int r_ = fl_ >> 6;                                                   \
            int blk_ = (fl_ >> 3) & 7;                                           \
            int d_ = ((blk_ ^ (r_ & 7)) << 3);                                   \
            gload_lds16(qb + (size_t)((m0s) + r_) * 1024 + 512 + h * 64 + d_,    \
                        &Ks[bufi][w * 512 + i_ * 2048]);                         \
        }                                                                        \
        _Pragma("unroll")                                                        \
        for (int i_ = 0; i_ < 2; ++i_) {                                         \
            int fl_ = t * 8 + i_ * 2048;                                         \
            int dr_ = fl_ >> 6;                                                  \
            int blk_ = (fl_ >> 3) & 7;                                           \
            int m_ = ((blk_ ^ (dr_ & 7)) << 3);                                  \
            gload_lds16(vb + (size_t)(h * 64 + dr_) * 512 + (m0s) + m_,          \
                        &Vs[bufi][w * 512 + i_ * 2048]);                         \
        }                                                                        \
    } while (0)

    KSTAGE(0, 0);
    __syncthreads();

    const f32x4 zero4 = {0.f, 0.f, 0.f, 0.f};
    f32x4 acc_o[4];
#pragma unroll
    for (int dj = 0; dj < 4; ++dj) acc_o[dj] = zero4;

    // per-lane stats for q-row = n0 + w*16 + l15 (identical across lg groups)
    float rmax = -3e38f, rsum = 0.f;

    const int qr = w * 16 + l15;
    bf16x8 aq[2];
#pragma unroll
    for (int kk = 0; kk < 2; ++kk)
        aq[kk] = *(const bf16x8*)&Qs[qr * 64 + (((kk * 4 + lg) ^ (qr & 7)) << 3)];

    const int qglob = n0 + w * 16 + l15;

    int cur = 0;
    for (int tile = 0; tile < 8; ++tile) {
        const int m0 = tile * 64;
        if (tile < 7) KSTAGE(cur ^ 1, m0 + 64);

        // swapped QK^T: s4[mi][reg] = S[m = m0 + mi*16 + lg*4 + reg][q = l15]
        f32x4 s4[4];
#pragma unroll
        for (int mi = 0; mi < 4; ++mi) s4[mi] = zero4;
#pragma unroll
        for (int kk = 0; kk < 2; ++kk) {
#pragma unroll
            for (int mi = 0; mi < 4; ++mi) {
                int mr = mi * 16 + l15;
                bf16x8 bk = *(const bf16x8*)&Ks[cur][mr * 64 + (((kk * 4 + lg) ^ (mr & 7)) << 3)];
                s4[mi] = __builtin_amdgcn_mfma_f32_16x16x32_bf16(bk, aq[kk], s4[mi], 0, 0, 0);
            }
        }

        // bias (log2 domain) + in-lane max
        const int ib = m0 + lg * 4 - qglob + 511;
        float tmax = -3e38f;
#pragma unroll
        for (int mi = 0; mi < 4; ++mi)
#pragma unroll
            for (int r = 0; r < 4; ++r) {
                float sv = s4[mi][r] * (0.125f * LOG2E_) + relh[ib + mi * 16 + r];
                s4[mi][r] = sv;
                tmax = fmaxf(tmax, sv);
            }
        tmax = fmaxf(tmax, __shfl_xor(tmax, 16));
        tmax = fmaxf(tmax, __shfl_xor(tmax, 32));

        // defer-max: rescale only when the new tile max exceeds rmax + 8
        if (!__all(tmax <= rmax + 8.f)) {
            float nm = fmaxf(rmax, tmax);
            float sc = __builtin_amdgcn_exp2f(rmax - nm);
            rmax = nm;
            rsum *= sc;
            float scl[4];
#pragma unroll
            for (int r = 0; r < 4; ++r)
                scl[r] = __shfl(sc, (lane & 48) | (lg * 4 + r));
#pragma unroll
            for (int dj = 0; dj < 4; ++dj)
#pragma unroll
                for (int r = 0; r < 4; ++r) acc_o[dj][r] *= scl[r];
        }

        // P = exp2(sv - rmax), in-lane sum
        float ts = 0.f;
#pragma unroll
        for (int mi = 0; mi < 4; ++mi)
#pragma unroll
            for (int r = 0; r < 4; ++r) {
                float p = __builtin_amdgcn_exp2f(s4[mi][r] - rmax);
                s4[mi][r] = p;
                ts += p;
            }
        ts += __shfl_xor(ts, 16);
        ts += __shfl_xor(ts, 32);
        rsum += ts;

        // pack P (m-consecutive pairs) and write to LDS, XOR-swizzled.
#pragma unroll
        for (int mi = 0; mi < 4; ++mi) {
            uint32_t w01 = cvt_pk_bf16(s4[mi][0], s4[mi][1]);
            uint32_t w23 = cvt_pk_bf16(s4[mi][2], s4[mi][3]);
            int blk = mi * 2 + (lg >> 1);
            int idx = w * 1024 + l15 * 64 + ((blk ^ (l15 & 7)) << 3) + ((lg & 1) << 2);
            *(uint2*)&Ps[idx] = make_uint2(w01, w23);
        }

        // PV: A = P (rows q at l15), B = V (rows d at l15)
#pragma unroll
        for (int kk = 0; kk < 2; ++kk) {
            bf16x8 ap = *(const bf16x8*)&Ps[w * 1024 + l15 * 64 + (((kk * 4 + lg) ^ (l15 & 7)) << 3)];
#pragma unroll
            for (int dj = 0; dj < 4; ++dj) {
                int dr = dj * 16 + l15;
                bf16x8 bv = *(const bf16x8*)&Vs[cur][dr * 64 + (((kk * 4 + lg) ^ (dr & 7)) << 3)];
                acc_o[dj] = __builtin_amdgcn_mfma_f32_16x16x32_bf16(ap, bv, acc_o[dj], 0, 0, 0);
            }
        }
        __syncthreads();            // drains prefetch before buffer swap
        cur ^= 1;
    }
#undef KSTAGE

    // redistribute 1/rsum from q=l15 lanes to q=lg*4+reg layout
    float inv = 1.f / rsum;
    float invr[4];
#pragma unroll
    for (int r = 0; r < 4; ++r)
        invr[r] = __shfl(inv, (lane & 48) | (lg * 4 + r));

    short* ob = attnT + (size_t)b * 512 * 512;
#pragma unroll
    for (int dj = 0; dj < 4; ++dj)
#pragma unroll
        for (int reg = 0; reg < 4; ++reg) {
            int nglob = n0 + w * 16 + lg * 4 + reg;
            ob[(size_t)nglob * 512 + h * 64 + dj * 16 + l15] =
                f2bf(acc_o[dj][reg] * invr[reg]);
        }
}

// ---------------------------------------------------------------------------
extern "C" void kernel_launch(void* const* d_in, const int* in_sizes, int n_in,
                              void* d_out, int out_size, void* d_ws, size_t ws_size,
                              hipStream_t stream)
{
    const float* x      = (const float*)d_in[0];
    const float* qkv_w  = (const float*)d_in[1];
    const float* qkv_b  = (const float*)d_in[2];
    const float* out_w  = (const float*)d_in[3];
    const float* out_b  = (const float*)d_in[4];
    const float* rel    = (const float*)d_in[5];
    const float* bn1_g  = (const float*)d_in[6];
    const float* bn1_b  = (const float*)d_in[7];
    const float* bn1_m  = (const float*)d_in[8];
    const float* bn1_v  = (const float*)d_in[9];
    const float* ffn1_w = (const float*)d_in[10];
    const float* ffn1_b = (const float*)d_in[11];
    const float* ffn2_w = (const float*)d_in[12];
    const float* ffn2_b = (const float*)d_in[13];
    const float* bn2_g  = (const float*)d_in[14];
    const float* bn2_b  = (const float*)d_in[15];
    const float* bn2_m  = (const float*)d_in[16];
    const float* bn2_v  = (const float*)d_in[17];

    float* out = (float*)d_out;
    short* ws  = (short*)d_ws;

    size_t off = 0;
    short* qkvw_bf = ws + off; off += (size_t)1536 * 512;   // cvt dest is
    short* outw_bf = ws + off; off += (size_t)512 * 512;    // contiguous
    short* f1w_bf  = ws + off; off += (size_t)1024 * 512;   // across these 4
    short* f2w_bf  = ws + off; off += (size_t)512 * 1024;
    short* xT      = ws + off; off += (size_t)B_ * 512 * 512;
    short* qkT     = ws + off; off += (size_t)B_ * 512 * 1024;
    short* vTb     = ws + off; off += (size_t)B_ * 512 * 512;
    short* attnT   = ws + off; off += (size_t)B_ * 512 * 512;
    short* h_bf    = ws + off; off += (size_t)B_ * 512 * 512;
    short* f1_bf   = ws + off; off += (size_t)B_ * 512 * 1024;

    const dim3 blk(256);

    // weight conversions (one launch, 524288 f32x4 groups)
    cvt_weights<<<dim3(524288 / 256), blk, 0, stream>>>(qkv_w, out_w, ffn1_w, ffn2_w, qkvw_bf);

    // x -> xT bf16 (also serves as BN1 residual, coalesced along c)
    transpose_x<<<dim3(8, 8, B_), blk, 0, stream>>>(x, xT);

    // 1) qkv projection (q,k -> qkT [n][1024]; v -> vTb [dv][n])
    gemm_mfma<EPI_QKV, 512, 1024, 12, 4><<<dim3(1536), blk, 0, stream>>>(
        xT, qkvw_bf, qkv_b, qkT, vTb, nullptr, nullptr, nullptr, nullptr, nullptr, nullptr);

    // 2) attention (1-D grid, XCD-affine decode)
    attn_mfma<<<dim3(2048), blk, 0, stream>>>(qkT, vTb, rel, attnT);

    // 3) out projection + residual(xT) + BN1 -> h_bf
    gemm_mfma<EPI_BN1, 512, 512, 4, 4><<<dim3(512), blk, 0, stream>>>(
        attnT, outw_bf, out_b, h_bf, nullptr, nullptr, xT, bn1_g, bn1_b, bn1_m, bn1_v);

    // 4) ffn1 + GELU -> f1_bf
    gemm_mfma<EPI_GELU, 512, 1024, 8, 4><<<dim3(1024), blk, 0, stream>>>(
        h_bf, f1w_bf, ffn1_b, f1_bf, nullptr, nullptr, nullptr, nullptr, nullptr, nullptr, nullptr);

    // 5) ffn2 + residual(h_bf) + BN2 -> out fp32 [b][c][n]
    gemm_mfma<EPI_BN2, 1024, 512, 4, 4><<<dim3(512), blk, 0, stream>>>(
        f1_bf, f2w_bf, ffn2_b, nullptr, nullptr, out, h_bf, bn2_g, bn2_b, bn2_m, bn2_v);
}